// Round 1
// baseline (114.171 us; speedup 1.0000x reference)
//
#include <hip/hip_runtime.h>

// exponential smoothing: out[b,0,:]=x[b,0,:]; out[b,t,:]=0.5*out[b,t-1,:]+0.5*x[b,t,:]
// x: (32, 4096, 512) fp32, c innermost.
// Chunked scan: T split into NCHUNK chunks; carry-in approximated by a
// WARM-step warm-up scan (alpha=0.5 => error <= 0.5^(WARM-1) ~ 5e-10).

#define BB 32
#define TT 4096
#define CC 512
#define NCHUNK 8
#define CHUNK (TT / NCHUNK)   // 512
#define WARM 32

__global__ __launch_bounds__(256) void ema_kernel(const float* __restrict__ x,
                                                  float* __restrict__ out) {
    const int tid = blockIdx.x * blockDim.x + threadIdx.x;
    const int c = tid & (CC - 1);          // lane -> c : coalesced
    const int bc = tid >> 9;               // / CC
    const int chunk = bc & (NCHUNK - 1);
    const int b = bc >> 3;                 // / NCHUNK

    const size_t base = (size_t)b * TT * CC + (size_t)c;
    const int t0 = chunk * CHUNK;

    float carry;
    int tstart;
    if (chunk == 0) {
        carry = x[base];                   // t = 0 passes through
        out[base] = carry;
        tstart = 1;
    } else {
        const int tw = t0 - WARM;
        carry = x[base + (size_t)tw * CC];
        #pragma unroll
        for (int j = 1; j < WARM; ++j) {
            carry = 0.5f * carry + 0.5f * x[base + (size_t)(tw + j) * CC];
        }
        tstart = t0;
    }

    const float* __restrict__ xp = x + base + (size_t)tstart * CC;
    float* __restrict__ op = out + base + (size_t)tstart * CC;
    const int n = t0 + CHUNK - tstart;

    #pragma unroll 8
    for (int i = 0; i < n; ++i) {
        carry = 0.5f * carry + 0.5f * xp[(size_t)i * CC];
        op[(size_t)i * CC] = carry;
    }
}

extern "C" void kernel_launch(void* const* d_in, const int* in_sizes, int n_in,
                              void* d_out, int out_size, void* d_ws, size_t ws_size,
                              hipStream_t stream) {
    const float* x = (const float*)d_in[0];
    float* out = (float*)d_out;
    const int total_threads = BB * CC * NCHUNK;   // 131072
    const int block = 256;
    const int grid = total_threads / block;       // 512
    ema_kernel<<<grid, block, 0, stream>>>(x, out);
}

// Round 3
// 85.093 us; speedup vs baseline: 1.3417x; 1.3417x over previous
//
#include <hip/hip_runtime.h>

// exponential smoothing (alpha=0.5): out[b,0,:]=x[b,0,:];
// out[b,t,:] = 0.5*out[b,t-1,:] + 0.5*x[b,t,:]
// x: (32, 4096, 512) fp32, c innermost.
//
// Chunked scan: T split into NCHUNK chunks; carry-in reconstructed by a
// WARM-step warm-up (alpha=0.5 => carry error <= 2^-(WARM-1) rel).
// float4 per thread (c-vectorized): 1 KB contiguous per wave-load, 4x fewer
// DRAM streams vs scalar. 65536 threads = 256 blocks = 1 block/CU.
// Native ext_vector type (not HIP_vector_type) so nontemporal builtins accept it.

typedef float f32x4 __attribute__((ext_vector_type(4)));

#define BB 32
#define TT 4096
#define CC 512
#define CV (CC / 4)           // 128 f32x4 per (b,t) row
#define NCHUNK 16
#define CHUNK (TT / NCHUNK)   // 256
#define WARM 16

__global__ __launch_bounds__(256) void ema_kernel(const f32x4* __restrict__ x,
                                                  f32x4* __restrict__ out) {
    const int tid = blockIdx.x * blockDim.x + threadIdx.x;
    const int cv = tid & (CV - 1);         // lane -> float4 column: coalesced
    const int bc = tid >> 7;               // / CV
    const int chunk = bc & (NCHUNK - 1);
    const int b = bc >> 4;                 // / NCHUNK

    const size_t base = (size_t)b * TT * CV + (size_t)cv;
    const int t0 = chunk * CHUNK;

    f32x4 carry;
    int tstart;
    if (chunk == 0) {
        carry = x[base];                   // t = 0 passes through
        out[base] = carry;
        tstart = 1;
    } else {
        const int tw = t0 - WARM;
        carry = x[base + (size_t)tw * CV];
        #pragma unroll
        for (int j = 1; j < WARM; ++j) {
            f32x4 v = x[base + (size_t)(tw + j) * CV];
            carry = 0.5f * (carry + v);
        }
        tstart = t0;
    }

    const f32x4* __restrict__ xp = x + base + (size_t)tstart * CV;
    f32x4* __restrict__ op = out + base + (size_t)tstart * CV;
    const int n = t0 + CHUNK - tstart;

    #pragma unroll 8
    for (int i = 0; i < n; ++i) {
        f32x4 v = xp[(size_t)i * CV];
        carry = 0.5f * (carry + v);
        __builtin_nontemporal_store(carry, &op[(size_t)i * CV]);
    }
}

extern "C" void kernel_launch(void* const* d_in, const int* in_sizes, int n_in,
                              void* d_out, int out_size, void* d_ws, size_t ws_size,
                              hipStream_t stream) {
    const f32x4* x = (const f32x4*)d_in[0];
    f32x4* out = (f32x4*)d_out;
    const int total_threads = BB * CV * NCHUNK;   // 65536
    const int block = 256;
    const int grid = total_threads / block;       // 256 = 1 block/CU
    ema_kernel<<<grid, block, 0, stream>>>(x, out);
}